// Round 5
// baseline (3684.654 us; speedup 1.0000x reference)
//
#include <hip/hip_runtime.h>
#include <math.h>

typedef _Float16 f16x8 __attribute__((ext_vector_type(8)));
typedef float    f32x4 __attribute__((ext_vector_type(4)));
typedef _Float16 half2v __attribute__((ext_vector_type(2)));

#define TT   2048
#define ROWB 640   // bytes per H' row: 288 f16 slots used, pad to 640B (XOR swz stays in-row)

// W'' (rows 0..511, cols 0..287):
//   k<256: w_hh[r][k]; 256..261: w_ih[r][k-256] (i,q,amp,amp3,sin,cos); k==262: b_ih[r]+b_hh[r]; else 0
// H'[c][k]: k<256: h_{t-1}[k]; 256..261: feats(x[t]); 262: 1.0; else 0.
// Wave wid owns f-tile (rows 16*wid..+15) and g-tile (rows 256+16*wid..+15).

__global__ __launch_bounds__(1024, 4)
void janet_mfma2(const float* __restrict__ x,
                 const float* __restrict__ w_ih,
                 const float* __restrict__ w_hh,
                 const float* __restrict__ b_ih,
                 const float* __restrict__ b_hh,
                 const float* __restrict__ fc_w,
                 const float* __restrict__ fc_b,
                 float* __restrict__ out)
{
    __shared__ __align__(16) unsigned char Hb[2][16][ROWB]; // ping-pong H'
    __shared__ float  pout[2][16][16][2];                   // per-wave out partials
    __shared__ float2 xring[64][16];                        // x staging ring
    __shared__ float  oring[64][16][2];                     // out staging ring

    const int tid  = threadIdx.x;
    const int wid  = tid >> 6;          // 16 waves
    const int lane = tid & 63;
    const int c    = lane & 15;         // batch column
    const int hi   = lane >> 4;         // k-quarter / row-quad
    const int swz  = (c & 7) << 4;      // 16B-block XOR swizzle
    const int b0   = blockIdx.x * 16;

    // ---------------- LDS init ----------------
    for (int i = tid; i < (2 * 16 * ROWB) / 4; i += 1024) ((unsigned int*)Hb)[i] = 0u;
    ((float*)pout)[tid] = 0.f;   // 1024 floats
    {   // prefill xring entries 0..63
        const int S = tid >> 4, cc = tid & 15;
        xring[S][cc] = *reinterpret_cast<const float2*>(x + ((size_t)(b0 + cc) * TT + S) * 2);
    }
    __syncthreads();
    if (tid < 32) {   // H'[c][262] = 1.0h in both buffers (byte 524)
        const int p = tid >> 4, cc = tid & 15;
        const int sz = (cc & 7) << 4;
        *(unsigned short*)((unsigned char*)&Hb[p][cc][0] + (524 ^ sz)) = 0x3C00;
    }

    // ---------------- A-fragments ----------------
    auto wval = [&](int r, int k) -> float {
        if (k < 256)  return w_hh[r * 256 + k];
        if (k < 262)  return w_ih[r * 6 + (k - 256)];
        if (k == 262) return b_ih[r] + b_hh[r];
        return 0.f;
    };
    const int rf = 16 * wid + c;         // f-tile row for this lane
    const int rg = 256 + 16 * wid + c;   // g-tile row
    f16x8 A0[9], A1[9];
    #pragma unroll
    for (int s = 0; s < 8; ++s) {
        const float4 v0 = *reinterpret_cast<const float4*>(&w_hh[rf * 256 + s * 32 + hi * 8]);
        const float4 v1 = *reinterpret_cast<const float4*>(&w_hh[rf * 256 + s * 32 + hi * 8 + 4]);
        const float4 u0 = *reinterpret_cast<const float4*>(&w_hh[rg * 256 + s * 32 + hi * 8]);
        const float4 u1 = *reinterpret_cast<const float4*>(&w_hh[rg * 256 + s * 32 + hi * 8 + 4]);
        f16x8 a, b;
        a[0]=(_Float16)v0.x; a[1]=(_Float16)v0.y; a[2]=(_Float16)v0.z; a[3]=(_Float16)v0.w;
        a[4]=(_Float16)v1.x; a[5]=(_Float16)v1.y; a[6]=(_Float16)v1.z; a[7]=(_Float16)v1.w;
        b[0]=(_Float16)u0.x; b[1]=(_Float16)u0.y; b[2]=(_Float16)u0.z; b[3]=(_Float16)u0.w;
        b[4]=(_Float16)u1.x; b[5]=(_Float16)u1.y; b[6]=(_Float16)u1.z; b[7]=(_Float16)u1.w;
        A0[s] = a; A1[s] = b;
    }
    {
        f16x8 a, b;
        #pragma unroll
        for (int j = 0; j < 8; ++j) {
            a[j] = (_Float16)wval(rf, 256 + hi * 8 + j);
            b[j] = (_Float16)wval(rg, 256 + hi * 8 + j);
        }
        A0[8] = a; A1[8] = b;
    }

    // fc fragment: this lane's 4 h-rows are 16*wid + 4*hi + j
    float fw0[4], fw1[4];
    #pragma unroll
    for (int j = 0; j < 4; ++j) {
        const int r = 16 * wid + 4 * hi + j;
        fw0[j] = fc_w[r];
        fw1[j] = fc_w[256 + r];
    }
    const float fcb0 = fc_b[0], fcb1 = fc_b[1];

    float hold[4] = {0.f, 0.f, 0.f, 0.f};
    __syncthreads();

    // feats(x[0]) -> Hb[1] (t=0 reads Hb[1]; h part is zeros = h_0)
    if (tid < 16) {
        const float2 xv = xring[0][tid];
        const float amp = sqrtf(xv.x * xv.x + xv.y * xv.y);
        const int sz = (tid & 7) << 4;
        unsigned char* dst = (unsigned char*)&Hb[1][tid][0];
        half2v f01; f01.x = (_Float16)xv.x;         f01.y = (_Float16)xv.y;
        half2v f23; f23.x = (_Float16)amp;          f23.y = (_Float16)(amp*amp*amp);
        half2v f45; f45.x = (_Float16)(xv.y/amp);   f45.y = (_Float16)(xv.x/amp);
        *(unsigned int*)(dst + (512 ^ sz)) = __builtin_bit_cast(unsigned int, f01);
        *(unsigned int*)(dst + (516 ^ sz)) = __builtin_bit_cast(unsigned int, f23);
        *(unsigned int*)(dst + (520 ^ sz)) = __builtin_bit_cast(unsigned int, f45);
    }
    __syncthreads();

    #pragma unroll 1
    for (int t = 0; t <= TT; ++t) {
        const int p_read  = (t + 1) & 1;
        const int p_write = t & 1;
        const bool doMain = (t < TT);

        // ---- bulk out flush: steps [t-34, t-3] done & stable ----
        if ((t & 31) == 2 && t >= 34 && tid < 512) {
            const int so = tid >> 4, cc = tid & 15;
            const int S  = (t - 34) + so;
            const float2 v = *reinterpret_cast<const float2*>(&oring[S & 63][cc][0]);
            *reinterpret_cast<float2*>(out + ((size_t)(b0 + cc) * TT + S) * 2) = v;
        }
        // ---- bulk x refill: entries [t+2, t+33] ----
        if ((t & 31) == 30 && tid < 512) {
            const int so = tid >> 4, cc = tid & 15;
            const int S  = t + 2 + so;
            if (S < TT)
                xring[S & 63][cc] =
                    *reinterpret_cast<const float2*>(x + ((size_t)(b0 + cc) * TT + S) * 2);
        }

        if (doMain) {
            // ---- MFMA: dm_f (C0) and dm_g (C1), 9 K-slices ----
            const unsigned char* hrow = (const unsigned char*)&Hb[p_read][c][0];
            f32x4 C0 = {0,0,0,0}, C1 = {0,0,0,0};
            #pragma unroll
            for (int s = 0; s < 9; ++s) {
                const f16x8 Bs = *(const f16x8*)(hrow + ((s * 64 + hi * 16) ^ swz));
                C0 = __builtin_amdgcn_mfma_f32_16x16x32_f16(A0[s], Bs, C0, 0, 0, 0);
                C1 = __builtin_amdgcn_mfma_f32_16x16x32_f16(A1[s], Bs, C1, 0, 0, 0);
            }
            // ---- gates + h update; rows 16*wid + 4*hi + j, col c ----
            float hn[4];
            #pragma unroll
            for (int j = 0; j < 4; ++j) {
                const float gf = 1.0f / (1.0f + __expf(-C0[j]));
                const float gg = 1.0f / (1.0f + __expf(-C1[j]));
                hn[j] = gg + gf * (hold[j] - gg);
                hold[j] = hn[j];
            }
            {
                half2v lo; lo.x = (_Float16)hn[0]; lo.y = (_Float16)hn[1];
                half2v hp; hp.x = (_Float16)hn[2]; hp.y = (_Float16)hn[3];
                uint2 v; v.x = __builtin_bit_cast(unsigned int, lo);
                         v.y = __builtin_bit_cast(unsigned int, hp);
                unsigned char* drow = (unsigned char*)&Hb[p_write][c][0];
                *(uint2*)(drow + ((32 * wid + 8 * hi) ^ swz)) = v;
            }
            // ---- out partials: po = fc_w(rows of this lane) . hn ----
            float po0 = fw0[0]*hn[0] + fw0[1]*hn[1] + fw0[2]*hn[2] + fw0[3]*hn[3];
            float po1 = fw1[0]*hn[0] + fw1[1]*hn[1] + fw1[2]*hn[2] + fw1[3]*hn[3];
            po0 += __shfl_xor(po0, 16); po0 += __shfl_xor(po0, 32);
            po1 += __shfl_xor(po1, 16); po1 += __shfl_xor(po1, 32);
            if (hi == 0)
                *reinterpret_cast<float2*>(&pout[p_write][wid][c][0]) = make_float2(po0, po1);
        }

        // ---- duty reduce: wave (t&15) finalizes step t-1 into oring ----
        if (t >= 1 && wid == (t & 15) && lane < 16) {
            float s0 = 0.f, s1 = 0.f;
            #pragma unroll
            for (int w = 0; w < 16; ++w) {
                const float2 v = *reinterpret_cast<const float2*>(&pout[p_read][w][lane][0]);
                s0 += v.x; s1 += v.y;
            }
            oring[(t - 1) & 63][lane][0] = s0 + fcb0;
            oring[(t - 1) & 63][lane][1] = s1 + fcb1;
        }

        // ---- feats(x[t+1]) -> Hb[p_write] ----
        if (tid < 16 && t + 1 < TT) {
            const float2 xv = xring[(t + 1) & 63][tid];
            const float amp = sqrtf(xv.x * xv.x + xv.y * xv.y);
            const int sz = (tid & 7) << 4;
            unsigned char* dst = (unsigned char*)&Hb[p_write][tid][0];
            half2v f01; f01.x = (_Float16)xv.x;         f01.y = (_Float16)xv.y;
            half2v f23; f23.x = (_Float16)amp;          f23.y = (_Float16)(amp*amp*amp);
            half2v f45; f45.x = (_Float16)(xv.y/amp);   f45.y = (_Float16)(xv.x/amp);
            *(unsigned int*)(dst + (512 ^ sz)) = __builtin_bit_cast(unsigned int, f01);
            *(unsigned int*)(dst + (516 ^ sz)) = __builtin_bit_cast(unsigned int, f23);
            *(unsigned int*)(dst + (520 ^ sz)) = __builtin_bit_cast(unsigned int, f45);
        }
        __syncthreads();
    }

    // epilogue: flush remaining steps 2016..2047
    if (tid < 512) {
        const int so = tid >> 4, cc = tid & 15;
        const int S  = 2016 + so;
        const float2 v = *reinterpret_cast<const float2*>(&oring[S & 63][cc][0]);
        *reinterpret_cast<float2*>(out + ((size_t)(b0 + cc) * TT + S) * 2) = v;
    }
}

extern "C" void kernel_launch(void* const* d_in, const int* in_sizes, int n_in,
                              void* d_out, int out_size, void* d_ws, size_t ws_size,
                              hipStream_t stream) {
    (void)in_sizes; (void)n_in; (void)out_size; (void)d_ws; (void)ws_size;
    const float* x    = (const float*)d_in[0];
    // d_in[1] = h_0 : reference ignores it (uses zeros)
    const float* w_ih = (const float*)d_in[2];
    const float* w_hh = (const float*)d_in[3];
    const float* b_ih = (const float*)d_in[4];
    const float* b_hh = (const float*)d_in[5];
    const float* fc_w = (const float*)d_in[6];
    const float* fc_b = (const float*)d_in[7];
    float* outp = (float*)d_out;

    hipLaunchKernelGGL(janet_mfma2, dim3(4), dim3(1024), 0, stream,
                       x, w_ih, w_hh, b_ih, b_hh, fc_w, fc_b, outp);
}

// Round 6
// 3667.781 us; speedup vs baseline: 1.0046x; 1.0046x over previous
//
#include <hip/hip_runtime.h>
#include <math.h>

typedef _Float16 f16x8 __attribute__((ext_vector_type(8)));
typedef float    f32x4 __attribute__((ext_vector_type(4)));
typedef _Float16 half2v __attribute__((ext_vector_type(2)));

#define TT   2048
#define ROWB 640   // bytes per H' row: 288 f16 slots used, pad (XOR swz stays in-row)

// W'' (rows 0..513, cols 0..287):
//   r<512:  k<256: w_hh[r][k]; 256..261: w_ih[r][k-256] (i,q,amp,amp3,sin,cos);
//           k==262: b_ih[r]+b_hh[r]; else 0
//   r=512/513 (fc): k<256: fc_w[r-512][k]; k==262: fc_b[r-512]; else 0
// H'[c][k]: k<256: h_{t-1}[k]; 256..261: feats(x[t]); 262: 1.0; else 0.
// Wave w owns f row-tiles 2w,2w+1 (rows 32w..+31) and g row-tiles (256+32w..+31).
// Wave 7 additionally owns the fc tile (rows 512..527; only 512/513 nonzero).

__global__ __launch_bounds__(512, 2)
void janet_mfma3(const float* __restrict__ x,
                 const float* __restrict__ w_ih,
                 const float* __restrict__ w_hh,
                 const float* __restrict__ b_ih,
                 const float* __restrict__ b_hh,
                 const float* __restrict__ fc_w,
                 const float* __restrict__ fc_b,
                 float* __restrict__ out)
{
    __shared__ __align__(16) unsigned char Hb[2][16][ROWB]; // ping-pong H'
    __shared__ float2 xring[64][16];                        // x staging ring
    __shared__ float2 oring[64][16];                        // out staging ring

    const int tid  = threadIdx.x;
    const int wid  = tid >> 6;          // 8 waves
    const int lane = tid & 63;
    const int c    = lane & 15;         // batch column
    const int hi   = lane >> 4;         // k-quarter / row-quad
    const int swz  = (c & 7) << 4;      // 16B-block XOR swizzle
    const int b0   = blockIdx.x * 16;

    // ---------------- LDS init ----------------
    for (int i = tid; i < (2 * 16 * ROWB) / 4; i += 512) ((unsigned int*)Hb)[i] = 0u;
    {   // prefill xring entries 0..63 (2 per thread)
        const int S = tid >> 4, cc = tid & 15;
        xring[S][cc] =
            *reinterpret_cast<const float2*>(x + ((size_t)(b0 + cc) * TT + S) * 2);
        xring[S + 32][cc] =
            *reinterpret_cast<const float2*>(x + ((size_t)(b0 + cc) * TT + S + 32) * 2);
    }
    __syncthreads();
    if (tid < 32) {   // H'[c][262] = 1.0h in both buffers (byte 524)
        const int p = tid >> 4, cc = tid & 15;
        const int sz = (cc & 7) << 4;
        *(unsigned short*)((unsigned char*)&Hb[p][cc][0] + (524 ^ sz)) = 0x3C00;
    }

    // ---------------- A-fragments ----------------
    auto wval = [&](int r, int k) -> float {
        if (r < 512) {
            if (k < 256)  return w_hh[r * 256 + k];
            if (k < 262)  return w_ih[r * 6 + (k - 256)];
            if (k == 262) return b_ih[r] + b_hh[r];
            return 0.f;
        }
        if (r < 514) {
            const int o = r - 512;
            if (k < 256)  return fc_w[o * 256 + k];
            if (k == 262) return fc_b[o];
            return 0.f;
        }
        return 0.f;
    };

    const int rows[4] = { 32 * wid + c,       32 * wid + 16 + c,
                          256 + 32 * wid + c, 256 + 32 * wid + 16 + c };
    f16x8 A[4][9];
    #pragma unroll
    for (int i = 0; i < 4; ++i) {
        const int r = rows[i];
        #pragma unroll
        for (int s = 0; s < 8; ++s) {
            const float4 v0 = *reinterpret_cast<const float4*>(&w_hh[r * 256 + s * 32 + hi * 8]);
            const float4 v1 = *reinterpret_cast<const float4*>(&w_hh[r * 256 + s * 32 + hi * 8 + 4]);
            f16x8 a;
            a[0]=(_Float16)v0.x; a[1]=(_Float16)v0.y; a[2]=(_Float16)v0.z; a[3]=(_Float16)v0.w;
            a[4]=(_Float16)v1.x; a[5]=(_Float16)v1.y; a[6]=(_Float16)v1.z; a[7]=(_Float16)v1.w;
            A[i][s] = a;
        }
        f16x8 a;
        #pragma unroll
        for (int j = 0; j < 8; ++j) a[j] = (_Float16)wval(r, 256 + hi * 8 + j);
        A[i][8] = a;
    }
    f16x8 Afc[9];
    if (wid == 7) {
        #pragma unroll
        for (int s = 0; s < 9; ++s) {
            f16x8 a;
            #pragma unroll
            for (int j = 0; j < 8; ++j) a[j] = (_Float16)wval(512 + c, s * 32 + hi * 8 + j);
            Afc[s] = a;
        }
    }

    float hold[2][4] = {{0.f,0.f,0.f,0.f},{0.f,0.f,0.f,0.f}};
    __syncthreads();

    // feats(x[0]) -> Hb[1] (t=0 reads Hb[1]; h part zeros = h_0)
    if (tid < 16) {
        const float2 xv = xring[0][tid];
        const float amp = sqrtf(xv.x * xv.x + xv.y * xv.y);
        const int sz = (tid & 7) << 4;
        unsigned char* dst = (unsigned char*)&Hb[1][tid][0];
        half2v f01; f01.x = (_Float16)xv.x;        f01.y = (_Float16)xv.y;
        half2v f23; f23.x = (_Float16)amp;         f23.y = (_Float16)(amp*amp*amp);
        half2v f45; f45.x = (_Float16)(xv.y/amp);  f45.y = (_Float16)(xv.x/amp);
        uint2 v; v.x = __builtin_bit_cast(unsigned int, f01);
                 v.y = __builtin_bit_cast(unsigned int, f23);
        *(uint2*)(dst + (512 ^ sz)) = v;
        *(unsigned int*)(dst + (520 ^ sz)) = __builtin_bit_cast(unsigned int, f45);
    }
    __syncthreads();

    #pragma unroll 1
    for (int t = 0; t <= TT; ++t) {
        const int  p_read  = (t + 1) & 1;
        const int  p_write = t & 1;
        const bool doMain  = (t < TT);

        // ---- bulk out flush: steps [t-34, t-3] are complete & stable ----
        if ((t & 31) == 2 && t >= 34) {
            const int so = tid >> 4, cc = tid & 15;
            const int S  = (t - 34) + so;
            *reinterpret_cast<float2*>(out + ((size_t)(b0 + cc) * TT + S) * 2) =
                oring[S & 63][cc];
        }
        // ---- bulk x refill: entries [t+2, t+33] ----
        if ((t & 31) == 30) {
            const int so = tid >> 4, cc = tid & 15;
            const int S  = t + 2 + so;
            if (S < TT)
                xring[S & 63][cc] =
                    *reinterpret_cast<const float2*>(x + ((size_t)(b0 + cc) * TT + S) * 2);
        }

        // ---- MFMA phase ----
        const unsigned char* hrow = (const unsigned char*)&Hb[p_read][c][0];
        f32x4 C0={0,0,0,0}, C1={0,0,0,0}, C2={0,0,0,0}, C3={0,0,0,0}, Cf={0,0,0,0};
        if (doMain) {
            #pragma unroll
            for (int s = 0; s < 9; ++s) {
                const f16x8 Bs = *(const f16x8*)(hrow + ((s * 64 + hi * 16) ^ swz));
                C0 = __builtin_amdgcn_mfma_f32_16x16x32_f16(A[0][s], Bs, C0, 0, 0, 0);
                C1 = __builtin_amdgcn_mfma_f32_16x16x32_f16(A[1][s], Bs, C1, 0, 0, 0);
                C2 = __builtin_amdgcn_mfma_f32_16x16x32_f16(A[2][s], Bs, C2, 0, 0, 0);
                C3 = __builtin_amdgcn_mfma_f32_16x16x32_f16(A[3][s], Bs, C3, 0, 0, 0);
                if (wid == 7)
                    Cf = __builtin_amdgcn_mfma_f32_16x16x32_f16(Afc[s], Bs, Cf, 0, 0, 0);
            }
        } else if (wid == 7) {   // t == TT: still need out[TT-1] = fc . h_{TT-1}
            #pragma unroll
            for (int s = 0; s < 9; ++s) {
                const f16x8 Bs = *(const f16x8*)(hrow + ((s * 64 + hi * 16) ^ swz));
                Cf = __builtin_amdgcn_mfma_f32_16x16x32_f16(Afc[s], Bs, Cf, 0, 0, 0);
            }
        }

        // ---- gates + h update + packed h write ----
        if (doMain) {
            unsigned char* drow = (unsigned char*)&Hb[p_write][c][0];
            #pragma unroll
            for (int ft = 0; ft < 2; ++ft) {
                const f32x4 f = ft ? C1 : C0;
                const f32x4 g = ft ? C3 : C2;
                float hn[4];
                #pragma unroll
                for (int j = 0; j < 4; ++j) {
                    const float gf = 1.0f / (1.0f + __expf(-f[j]));
                    const float gg = 1.0f / (1.0f + __expf(-g[j]));
                    hn[j] = gg + gf * (hold[ft][j] - gg);
                    hold[ft][j] = hn[j];
                }
                half2v lo; lo.x = (_Float16)hn[0]; lo.y = (_Float16)hn[1];
                half2v hp; hp.x = (_Float16)hn[2]; hp.y = (_Float16)hn[3];
                uint2 v; v.x = __builtin_bit_cast(unsigned int, lo);
                         v.y = __builtin_bit_cast(unsigned int, hp);
                *(uint2*)(drow + ((64 * wid + 32 * ft + 8 * hi) ^ swz)) = v;
            }
        }

        // ---- fc output: Cf regs 0/1 (hi==0 lanes) = out[t-1] (fc_b via bias col) ----
        if (wid == 7 && hi == 0 && t >= 1)
            oring[(t - 1) & 63][c] = make_float2(Cf[0], Cf[1]);

        // ---- feats(x[t+1]) -> Hb[p_write] ----
        if (wid == 0 && lane < 16 && t + 1 < TT) {
            const float2 xv = xring[(t + 1) & 63][lane];
            const float amp = sqrtf(xv.x * xv.x + xv.y * xv.y);
            const int sz = (lane & 7) << 4;
            unsigned char* dst = (unsigned char*)&Hb[p_write][lane][0];
            half2v f01; f01.x = (_Float16)xv.x;        f01.y = (_Float16)xv.y;
            half2v f23; f23.x = (_Float16)amp;         f23.y = (_Float16)(amp*amp*amp);
            half2v f45; f45.x = (_Float16)(xv.y/amp);  f45.y = (_Float16)(xv.x/amp);
            uint2 v; v.x = __builtin_bit_cast(unsigned int, f01);
                     v.y = __builtin_bit_cast(unsigned int, f23);
            *(uint2*)(dst + (512 ^ sz)) = v;
            *(unsigned int*)(dst + (520 ^ sz)) = __builtin_bit_cast(unsigned int, f45);
        }
        __syncthreads();
    }

    // epilogue: flush remaining steps 2016..2047
    {
        const int so = tid >> 4, cc = tid & 15;
        const int S  = 2016 + so;
        *reinterpret_cast<float2*>(out + ((size_t)(b0 + cc) * TT + S) * 2) =
            oring[S & 63][cc];
    }
}

extern "C" void kernel_launch(void* const* d_in, const int* in_sizes, int n_in,
                              void* d_out, int out_size, void* d_ws, size_t ws_size,
                              hipStream_t stream) {
    (void)in_sizes; (void)n_in; (void)out_size; (void)d_ws; (void)ws_size;
    const float* x    = (const float*)d_in[0];
    // d_in[1] = h_0 : reference ignores it (uses zeros)
    const float* w_ih = (const float*)d_in[2];
    const float* w_hh = (const float*)d_in[3];
    const float* b_ih = (const float*)d_in[4];
    const float* b_hh = (const float*)d_in[5];
    const float* fc_w = (const float*)d_in[6];
    const float* fc_b = (const float*)d_in[7];
    float* outp = (float*)d_out;

    hipLaunchKernelGGL(janet_mfma3, dim3(4), dim3(512), 0, stream,
                       x, w_ih, w_hh, b_ih, b_hh, fc_w, fc_b, outp);
}